// Round 16
// baseline (308.535 us; speedup 1.0000x reference)
//
#include <hip/hip_runtime.h>
#include <math.h>
#include <stdint.h>

typedef unsigned short u16;
typedef unsigned int u32;
typedef __attribute__((ext_vector_type(8))) __bf16 bf16x8;
typedef __attribute__((ext_vector_type(4))) float f32x4;

#define AS1 __attribute__((address_space(1)))
#define AS3 __attribute__((address_space(3)))

__device__ __forceinline__ void stage16(const void* g, void* l) {
    __builtin_amdgcn_global_load_lds((const AS1 void*)(uintptr_t)g,
                                     (AS3 void*)(uintptr_t)l, 16, 0, 0);
}

__device__ __forceinline__ u16 f2bf(float f) {
    u32 u = __float_as_uint(f);
    u += 0x7fffu + ((u >> 16) & 1u);
    return (u16)(u >> 16);
}

__device__ __forceinline__ float bf2f(u16 v) {
    u32 u = ((u32)v) << 16;
    return __uint_as_float(u);
}

// ---------------- LayerNorm: 256 thr per row of 768, wave-shfl reduce, bf16 out ----------------
__global__ __launch_bounds__(256) void ln_kernel(const float* __restrict__ x,
                                                 const float* __restrict__ g,
                                                 const float* __restrict__ b,
                                                 u16* __restrict__ out) {
    __shared__ float s8[8];
    int row = blockIdx.x;
    int tid = threadIdx.x;
    const int w = tid >> 6;
    const float* xr = x + (size_t)row * 768;
    float x0 = xr[tid], x1 = xr[tid + 256], x2 = xr[tid + 512];

    float sum = x0 + x1 + x2;
#pragma unroll
    for (int off = 32; off; off >>= 1) sum += __shfl_xor(sum, off);
    if ((tid & 63) == 0) s8[w] = sum;
    __syncthreads();
    float mu = (s8[0] + s8[1] + s8[2] + s8[3]) * (1.0f / 768.0f);

    float d0 = x0 - mu, d1 = x1 - mu, d2 = x2 - mu;
    float sq = d0 * d0 + d1 * d1 + d2 * d2;
#pragma unroll
    for (int off = 32; off; off >>= 1) sq += __shfl_xor(sq, off);
    if ((tid & 63) == 0) s8[4 + w] = sq;
    __syncthreads();
    float var = (s8[4] + s8[5] + s8[6] + s8[7]) * (1.0f / 768.0f);
    float rs = rsqrtf(var + 1e-5f);

    u16* orow = out + (size_t)row * 768;
    orow[tid]       = f2bf(d0 * rs * g[tid]       + b[tid]);
    orow[tid + 256] = f2bf(d1 * rs * g[tid + 256] + b[tid + 256]);
    orow[tid + 512] = f2bf(d2 * rs * g[tid + 512] + b[tid + 512]);
}

// ---------------- transpose + fp32->bf16 convert: W[K][N] -> Wt[N][K] ----------------
__global__ __launch_bounds__(256) void transpose_bf16(const float* __restrict__ W,
                                                      u16* __restrict__ Wt,
                                                      int K, int N) {
    __shared__ float t[32][33];
    int tx = threadIdx.x, ty = threadIdx.y;
    int n0 = blockIdx.x * 32, k0 = blockIdx.y * 32;
#pragma unroll
    for (int j = 0; j < 32; j += 8)
        t[ty + j][tx] = W[(size_t)(k0 + ty + j) * N + n0 + tx];
    __syncthreads();
#pragma unroll
    for (int j = 0; j < 32; j += 8)
        Wt[(size_t)(n0 + ty + j) * K + k0 + tx] = f2bf(t[tx][ty + j]);
}

// ---- fused 4x 768x768 transpose (Wq,Wk,Wv -> Wqkvt sections; Wo -> Wot) ----
__global__ __launch_bounds__(256) void transpose4_768(const float* __restrict__ Wq,
                                                      const float* __restrict__ Wk,
                                                      const float* __restrict__ Wv,
                                                      const float* __restrict__ Wo,
                                                      u16* __restrict__ Wqkvt,
                                                      u16* __restrict__ Wot) {
    __shared__ float t[32][33];
    const int z = blockIdx.z;
    const float* W = (z == 0) ? Wq : (z == 1) ? Wk : (z == 2) ? Wv : Wo;
    u16* Wt = (z == 3) ? Wot : (Wqkvt + (size_t)z * 768 * 768);
    int tx = threadIdx.x, ty = threadIdx.y;
    int n0 = blockIdx.x * 32, k0 = blockIdx.y * 32;
#pragma unroll
    for (int j = 0; j < 32; j += 8)
        t[ty + j][tx] = W[(size_t)(k0 + ty + j) * 768 + n0 + tx];
    __syncthreads();
#pragma unroll
    for (int j = 0; j < 32; j += 8)
        Wt[(size_t)(n0 + ty + j) * 768 + k0 + tx] = f2bf(t[tx][ty + j]);
}

// ---------------- V transpose: qkv v-region [8192][2304] -> Vt[96][64][1024] ----------------
__global__ __launch_bounds__(256) void vt_kernel(const u16* __restrict__ qkv,
                                                 u16* __restrict__ Vt) {
    __shared__ u16 t[32][34];
    const int tx = threadIdx.x, ty = threadIdx.y;
    const int s0 = blockIdx.x * 32, d0 = blockIdx.y * 32, bh = blockIdx.z;
    const int b = bh / 12, h = bh % 12;
#pragma unroll
    for (int j = 0; j < 32; j += 8)
        t[ty + j][tx] = qkv[((size_t)(b * 1024) + s0 + ty + j) * 2304 + 1536 + h * 64 + d0 + tx];
    __syncthreads();
#pragma unroll
    for (int j = 0; j < 32; j += 8)
        Vt[((size_t)bh * 64 + d0 + ty + j) * 1024 + s0 + tx] = t[tx][ty + j];
}

// ---------------- bf16 MFMA GEMM: 128^2, BK=32, triple buffer, 2-deep, unroll-3 ----------------
// WGM=8 supertile remap: within each XCD chunk, walk 8 brows per bcol so the
// ~96 concurrently-resident blocks per XCD cover ~12 bcols x 8 brows ->
// concurrent L2 working set A 1.6MB + B 2.4MB < 4MB (vs 5.5MB with bcol-fastest
// order, which thrashed B and exposed HBM latency every iteration).
__global__ __launch_bounds__(256, 3) void gemm_k32(
    const u16* __restrict__ A, const u16* __restrict__ Bt,
    const float* __restrict__ bias, const float* __restrict__ res,
    float* __restrict__ outF, u16* __restrict__ outB,
    int N, int K, int act) {
    __shared__ char lds[49152];
    const int tid = threadIdx.x, lane = tid & 63, wid = tid >> 6;
    const int l15 = lane & 15, lk = lane >> 4;
    const int wrow = (wid >> 1) * 64, wcol = (wid & 1) * 64;

    int wg = blockIdx.y * gridDim.x + blockIdx.x;
    const int nwg = gridDim.x * gridDim.y;
    wg = (wg & 7) * (nwg >> 3) + (wg >> 3);   // bijective XCD swizzle (nwg % 8 == 0)
    // WGM=8 supertile (gridDim.y == 64, divisible by 8)
    const int gx = gridDim.x;
    const int strip = wg / (gx * 8);
    const int rem = wg - strip * gx * 8;
    const int brow = (strip * 8 + (rem & 7)) * 128;
    const int bcol = (rem >> 3) * 128;

    const size_t K2 = (size_t)K * 2;
    const char* Abase = (const char*)A + (size_t)brow * K2;
    const char* Bbase = (const char*)Bt + (size_t)bcol * K2;

    int srow[2], scol[2];
#pragma unroll
    for (int j = 0; j < 2; ++j) {
        const int L = j * 4096 + tid * 16;
        srow[j] = L >> 6;
        scol[j] = (L & 63) ^ (((srow[j] >> 1) & 3) << 4);
    }

    const int nt = K >> 5;  // 24 or 96: divisible by 3

    auto stage_tile = [&](int t, char* dst) {
#pragma unroll
        for (int j = 0; j < 2; ++j) {
            const size_t off = (size_t)srow[j] * K2 + (size_t)t * 64 + scol[j];
            stage16(Abase + off, dst + j * 4096 + tid * 16);
            stage16(Bbase + off, dst + 8192 + j * 4096 + tid * 16);
        }
    };

    f32x4 acc[4][4] = {};

    stage_tile(0, lds);
    stage_tile(1, lds + 16384);

    auto iter = [&](int t, char* buf, char* nxt) {
        if (t + 1 < nt) asm volatile("s_waitcnt vmcnt(4)\n\ts_barrier" ::: "memory");
        else            asm volatile("s_waitcnt vmcnt(0)\n\ts_barrier" ::: "memory");
        __builtin_amdgcn_sched_barrier(0);

        if (t + 2 < nt) stage_tile(t + 2, nxt);

        const char* As = buf;
        const char* Bs = buf + 8192;
        bf16x8 af[4], bfv[4];
#pragma unroll
        for (int m = 0; m < 4; ++m) {
            const int row = wrow + m * 16 + l15;
            af[m] = *(const bf16x8*)(As + row * 64 +
                                     ((lk * 16) ^ (((row >> 1) & 3) << 4)));
        }
#pragma unroll
        for (int n = 0; n < 4; ++n) {
            const int row = wcol + n * 16 + l15;
            bfv[n] = *(const bf16x8*)(Bs + row * 64 +
                                      ((lk * 16) ^ (((row >> 1) & 3) << 4)));
        }
        __builtin_amdgcn_s_setprio(1);
#pragma unroll
        for (int m = 0; m < 4; ++m)
#pragma unroll
            for (int n = 0; n < 4; ++n)
                acc[m][n] = __builtin_amdgcn_mfma_f32_16x16x32_bf16(af[m], bfv[n], acc[m][n], 0, 0, 0);
        __builtin_amdgcn_s_setprio(0);
    };

    for (int t = 0; t < nt; t += 3) {
        iter(t,     lds,         lds + 32768);
        iter(t + 1, lds + 16384, lds);
        iter(t + 2, lds + 32768, lds + 16384);
    }

    if (outB) {
        // coalesced bf16 epilogue via LDS (bufs 0-1 dead after final top barrier)
        u16* ctile = (u16*)lds;  // [128][128] u16 = 32KB
#pragma unroll
        for (int m = 0; m < 4; ++m)
#pragma unroll
            for (int n = 0; n < 4; ++n)
#pragma unroll
                for (int r = 0; r < 4; ++r) {
                    float v = acc[m][n][r];
                    int col = wcol + n * 16 + l15;
                    if (bias) v += bias[bcol + col];
                    if (act) v = 0.5f * v * (1.0f + erff(v * 0.70710678118654752f));
                    ctile[(wrow + m * 16 + lk * 4 + r) * 128 + col] = f2bf(v);
                }
        __syncthreads();
#pragma unroll
        for (int pass = 0; pass < 8; ++pass) {
            const int idx = pass * 256 + tid;
            const int row = idx >> 4;
            const int seg = idx & 15;
            *(bf16x8*)(outB + (size_t)(brow + row) * N + bcol + seg * 8) =
                *(const bf16x8*)(ctile + row * 128 + seg * 8);
        }
    } else {
#pragma unroll
        for (int m = 0; m < 4; ++m)
#pragma unroll
            for (int n = 0; n < 4; ++n)
#pragma unroll
                for (int r = 0; r < 4; ++r) {
                    int row = brow + wrow + m * 16 + lk * 4 + r;
                    int col = bcol + wcol + n * 16 + l15;
                    float v = acc[m][n][r];
                    if (bias) v += bias[col];
                    if (act) v = 0.5f * v * (1.0f + erff(v * 0.70710678118654752f));
                    if (res) v += res[(size_t)row * N + col];
                    outF[(size_t)row * N + col] = v;  // f32: 64B line-aligned runs
                }
    }
}

// ---------------- split-K=2 GEMM for FF2: z-half of K, bf16 partial out ----------------
__global__ __launch_bounds__(256, 3) void gemm_splitk(
    const u16* __restrict__ A, const u16* __restrict__ Bt,
    u16* __restrict__ p0, u16* __restrict__ p1, int N, int K) {
    __shared__ char lds[49152];
    const int tid = threadIdx.x, lane = tid & 63, wid = tid >> 6;
    const int l15 = lane & 15, lk = lane >> 4;
    const int wrow = (wid >> 1) * 64, wcol = (wid & 1) * 64;
    const int z = blockIdx.z;
    const int Kh = K >> 1;

    int wg = blockIdx.y * gridDim.x + blockIdx.x;
    const int nwg = gridDim.x * gridDim.y;
    wg = (wg & 7) * (nwg >> 3) + (wg >> 3);
    const int brow = (wg / gridDim.x) * 128;
    const int bcol = (wg % gridDim.x) * 128;

    const size_t K2 = (size_t)K * 2;
    const char* Abase = (const char*)A + (size_t)brow * K2 + (size_t)z * Kh * 2;
    const char* Bbase = (const char*)Bt + (size_t)bcol * K2 + (size_t)z * Kh * 2;

    int srow[2], scol[2];
#pragma unroll
    for (int j = 0; j < 2; ++j) {
        const int L = j * 4096 + tid * 16;
        srow[j] = L >> 6;
        scol[j] = (L & 63) ^ (((srow[j] >> 1) & 3) << 4);
    }

    const int nt = Kh >> 5;  // 48: divisible by 3

    auto stage_tile = [&](int t, char* dst) {
#pragma unroll
        for (int j = 0; j < 2; ++j) {
            const size_t off = (size_t)srow[j] * K2 + (size_t)t * 64 + scol[j];
            stage16(Abase + off, dst + j * 4096 + tid * 16);
            stage16(Bbase + off, dst + 8192 + j * 4096 + tid * 16);
        }
    };

    f32x4 acc[4][4] = {};

    stage_tile(0, lds);
    stage_tile(1, lds + 16384);

    auto iter = [&](int t, char* buf, char* nxt) {
        if (t + 1 < nt) asm volatile("s_waitcnt vmcnt(4)\n\ts_barrier" ::: "memory");
        else            asm volatile("s_waitcnt vmcnt(0)\n\ts_barrier" ::: "memory");
        __builtin_amdgcn_sched_barrier(0);

        if (t + 2 < nt) stage_tile(t + 2, nxt);

        const char* As = buf;
        const char* Bs = buf + 8192;
        bf16x8 af[4], bfv[4];
#pragma unroll
        for (int m = 0; m < 4; ++m) {
            const int row = wrow + m * 16 + l15;
            af[m] = *(const bf16x8*)(As + row * 64 +
                                     ((lk * 16) ^ (((row >> 1) & 3) << 4)));
        }
#pragma unroll
        for (int n = 0; n < 4; ++n) {
            const int row = wcol + n * 16 + l15;
            bfv[n] = *(const bf16x8*)(Bs + row * 64 +
                                      ((lk * 16) ^ (((row >> 1) & 3) << 4)));
        }
        __builtin_amdgcn_s_setprio(1);
#pragma unroll
        for (int m = 0; m < 4; ++m)
#pragma unroll
            for (int n = 0; n < 4; ++n)
                acc[m][n] = __builtin_amdgcn_mfma_f32_16x16x32_bf16(af[m], bfv[n], acc[m][n], 0, 0, 0);
        __builtin_amdgcn_s_setprio(0);
    };

    for (int t = 0; t < nt; t += 3) {
        iter(t,     lds,         lds + 32768);
        iter(t + 1, lds + 16384, lds);
        iter(t + 2, lds + 32768, lds + 16384);
    }

    u16* outP = z ? p1 : p0;
    u16* ctile = (u16*)lds;
#pragma unroll
    for (int m = 0; m < 4; ++m)
#pragma unroll
        for (int n = 0; n < 4; ++n)
#pragma unroll
            for (int r = 0; r < 4; ++r)
                ctile[(wrow + m * 16 + lk * 4 + r) * 128 + wcol + n * 16 + l15] =
                    f2bf(acc[m][n][r]);
    __syncthreads();
#pragma unroll
    for (int pass = 0; pass < 8; ++pass) {
        const int idx = pass * 256 + tid;
        const int row = idx >> 4;
        const int seg = idx & 15;
        *(bf16x8*)(outP + (size_t)(brow + row) * N + bcol + seg * 8) =
            *(const bf16x8*)(ctile + row * 128 + seg * 8);
    }
}

// ---------------- FF2 reduce: out = x2 + b2 + p0 + p1 ----------------
__global__ __launch_bounds__(256) void ff2_reduce(const float* __restrict__ x2,
                                                  const float* __restrict__ b2,
                                                  const u16* __restrict__ p0,
                                                  const u16* __restrict__ p1,
                                                  float* __restrict__ out) {
    const size_t i = ((size_t)blockIdx.x * 256 + threadIdx.x) * 4;
    const float4 a = *(const float4*)(x2 + i);
    const int col = (int)(i % 768);
    const float4 bb = *(const float4*)(b2 + col);
    const ushort4 q0 = *(const ushort4*)(p0 + i);
    const ushort4 q1 = *(const ushort4*)(p1 + i);
    float4 o;
    o.x = a.x + bb.x + bf2f(q0.x) + bf2f(q1.x);
    o.y = a.y + bb.y + bf2f(q0.y) + bf2f(q1.y);
    o.z = a.z + bb.z + bf2f(q0.z) + bf2f(q1.z);
    o.w = a.w + bb.w + bf2f(q0.w) + bf2f(q1.w);
    *(float4*)(out + i) = o;
}

// ---------------- MFMA flash attention: balanced q-tile PAIRS, dbuf staging ----------------
__global__ __launch_bounds__(256) void attn_mfma(const u16* __restrict__ qkv,
                                                 const u16* __restrict__ Vt,
                                                 u16* __restrict__ obf) {
    __shared__ char lds[40960];
    const int tid = threadIdx.x, lane = tid & 63, w = tid >> 6;
    const int g = lane >> 4, l15 = lane & 15;

    int wg = blockIdx.y * gridDim.x + blockIdx.x;
    const int nwg = gridDim.x * gridDim.y;
    wg = (wg & 7) * (nwg >> 3) + (wg >> 3);
    const int p = wg / 96;               // 0..7: pair index (uniform per XCD chunk)
    const int bh = wg % 96;
    const int h = bh % 12, b = bh / 12;
    const float scale = 0.03608439182435161f;  // 768^-0.5 (C, not hs, per reference)

    const int sub = ((lane & 7) * 16) ^ ((lane >> 3) << 4);
    const int r0 = 16 * w + (lane >> 3);
    const int dstOff = 2 * w * 1024 + lane * 16;
    const int swzA = (l15 & 7) << 4;
    char* Pw = lds + 32768 + w * 2048;

#pragma unroll 1
    for (int half = 0; half < 2; ++half) {
        const int qb = half ? p : (15 - p);   // heavy tile first
        const int t0 = qb * 64;

        const size_t qrow = ((size_t)b * 1024 + t0 + 16 * w + l15) * 2304 + h * 64;
        const bf16x8 qf0 = *(const bf16x8*)(qkv + qrow + 8 * g);
        const bf16x8 qf1 = *(const bf16x8*)(qkv + qrow + 8 * g + 32);

        const char* kSrc = (const char*)qkv + ((size_t)(b * 1024 + r0) * 2304 + 768 + h * 64) * 2 + sub;
        const char* vSrc = (const char*)Vt + ((size_t)(bh * 64 + r0) * 1024) * 2 + sub;

        stage16(kSrc,            lds + dstOff);
        stage16(kSrc + 8 * 4608, lds + dstOff + 1024);
        stage16(vSrc,            lds + 8192 + dstOff);
        stage16(vSrc + 8 * 2048, lds + 8192 + dstOff + 1024);
        kSrc += 64 * 4608; vSrc += 128;
        __syncthreads();

        float m_r[4] = {-1e30f, -1e30f, -1e30f, -1e30f};
        float l_r[4] = {0.f, 0.f, 0.f, 0.f};
        f32x4 oacc[4] = {};

        for (int c = 0; c <= qb; ++c) {
            if (c < qb) {
                char* dst = lds + ((c + 1) & 1) * 16384;
                stage16(kSrc,            dst + dstOff);
                stage16(kSrc + 8 * 4608, dst + dstOff + 1024);
                stage16(vSrc,            dst + 8192 + dstOff);
                stage16(vSrc + 8 * 2048, dst + 8192 + dstOff + 1024);
                kSrc += 64 * 4608; vSrc += 128;
                asm volatile("s_waitcnt vmcnt(4)\n\ts_barrier" ::: "memory");
            } else {
                asm volatile("s_waitcnt vmcnt(0)\n\ts_barrier" ::: "memory");
            }
            __builtin_amdgcn_sched_barrier(0);

            const char* bufK = lds + (c & 1) * 16384;
            const char* bufV = bufK + 8192;

            f32x4 sacc[4] = {};
#pragma unroll
            for (int st = 0; st < 4; ++st) {
                const char* krow = bufK + (l15 + 16 * st) * 128;
                const bf16x8 kf0 = *(const bf16x8*)(krow + ((16 * g) ^ swzA));
                const bf16x8 kf1 = *(const bf16x8*)(krow + ((16 * g + 64) ^ swzA));
                sacc[st] = __builtin_amdgcn_mfma_f32_16x16x32_bf16(qf0, kf0, sacc[st], 0, 0, 0);
                sacc[st] = __builtin_amdgcn_mfma_f32_16x16x32_bf16(qf1, kf1, sacc[st], 0, 0, 0);
            }

            const bool diag = (c == qb);
#pragma unroll
            for (int r = 0; r < 4; ++r) {
                float sv0 = sacc[0][r] * scale, sv1 = sacc[1][r] * scale;
                float sv2 = sacc[2][r] * scale, sv3 = sacc[3][r] * scale;
                if (diag) {
                    const int trel = 16 * w + 4 * g + r;
                    if (l15 +  0 > trel) sv0 = -1e30f;
                    if (l15 + 16 > trel) sv1 = -1e30f;
                    if (l15 + 32 > trel) sv2 = -1e30f;
                    if (l15 + 48 > trel) sv3 = -1e30f;
                }
                float mx = fmaxf(fmaxf(sv0, sv1), fmaxf(sv2, sv3));
#pragma unroll
                for (int off = 1; off < 16; off <<= 1) mx = fmaxf(mx, __shfl_xor(mx, off));
                if (mx > m_r[r]) {
                    const float corr = __expf(m_r[r] - mx);
                    m_r[r] = mx;
                    l_r[r] *= corr;
                    oacc[0][r] *= corr; oacc[1][r] *= corr;
                    oacc[2][r] *= corr; oacc[3][r] *= corr;
                }
                const float p0 = __expf(sv0 - m_r[r]), p1 = __expf(sv1 - m_r[r]);
                const float p2 = __expf(sv2 - m_r[r]), p3 = __expf(sv3 - m_r[r]);
                float ps = p0 + p1 + p2 + p3;
#pragma unroll
                for (int off = 1; off < 16; off <<= 1) ps += __shfl_xor(ps, off);
                l_r[r] += ps;
                const int q = 4 * g + r;
                char* pr = Pw + q * 128;
                const int sw = (q & 7) << 4;
                *(u16*)(pr + ((l15 * 2 +  0) ^ sw)) = f2bf(p0);
                *(u16*)(pr + ((l15 * 2 + 32) ^ sw)) = f2bf(p1);
                *(u16*)(pr + ((l15 * 2 + 64) ^ sw)) = f2bf(p2);
                *(u16*)(pr + ((l15 * 2 + 96) ^ sw)) = f2bf(p3);
            }

#pragma unroll
            for (int kc = 0; kc < 2; ++kc) {
                const bf16x8 pa = *(const bf16x8*)(Pw + l15 * 128 + ((16 * g + 64 * kc) ^ swzA));
#pragma unroll
                for (int dt = 0; dt < 4; ++dt) {
                    const int d = l15 + 16 * dt;
                    const bf16x8 vf = *(const bf16x8*)(bufV + d * 128 +
                                       ((16 * g + 64 * kc) ^ ((d & 7) << 4)));
                    oacc[dt] = __builtin_amdgcn_mfma_f32_16x16x32_bf16(pa, vf, oacc[dt], 0, 0, 0);
                }
            }
            asm volatile("s_barrier" ::: "memory");
        }

        const size_t orow0 = ((size_t)b * 1024 + t0 + 16 * w) * 768 + h * 64;
#pragma unroll
        for (int r = 0; r < 4; ++r) {
            const float inv = 1.0f / l_r[r];
            const size_t orow = orow0 + (size_t)(4 * g + r) * 768;
#pragma unroll
            for (int dt = 0; dt < 4; ++dt)
                obf[orow + 16 * dt + l15] = f2bf(oacc[dt][r] * inv);
        }
    }
}

extern "C" void kernel_launch(void* const* d_in, const int* in_sizes, int n_in,
                              void* d_out, int out_size, void* d_ws, size_t ws_size,
                              hipStream_t stream) {
    const float* x   = (const float*)d_in[0];
    const float* Wq  = (const float*)d_in[1];
    const float* Wk  = (const float*)d_in[2];
    const float* Wv  = (const float*)d_in[3];
    const float* Wo  = (const float*)d_in[4];
    const float* bo  = (const float*)d_in[5];
    const float* W1  = (const float*)d_in[6];
    const float* b1  = (const float*)d_in[7];
    const float* W2  = (const float*)d_in[8];
    const float* b2  = (const float*)d_in[9];
    const float* g1  = (const float*)d_in[10];
    const float* be1 = (const float*)d_in[11];
    const float* g2  = (const float*)d_in[12];
    const float* be2 = (const float*)d_in[13];
    float* out = (float*)d_out;

    char* ws = (char*)d_ws;
    u16* qkv_bf = (u16*)(ws);              // [8192][2304] bf16  37.7MB (dead after attn)
    u16* ff1_bf = (u16*)(ws);              // [8192][3072] bf16  50.3MB (reuses qkv region)
    float* x2   = (float*)(ws + 50331648); // [8192][768]  f32   25.2MB
    u16* h_bf   = (u16*)(ws + 75497472);   // [8192][768]  bf16  12.6MB (dead after FF1)
    u16* o_bf   = (u16*)(ws + 88080384);   // [8192][768]  bf16  12.6MB (dead after Wo)
    u16* p0_bf  = h_bf;                    // FF2 split-K partial 0 (reuses h_bf)
    u16* p1_bf  = o_bf;                    // FF2 split-K partial 1 (reuses o_bf)
    u16* Wqkvt  = (u16*)(ws + 100663296);  // [2304][768]  bf16   3.5MB
    u16* W1t    = (u16*)(ws + 104202240);  // [3072][768]  bf16   4.7MB
    u16* W2t    = (u16*)(ws + 108920832);  // [768][3072]  bf16   4.7MB
    u16* Wot    = (u16*)(ws + 113639424);  // [768][768]   bf16   1.2MB
    u16* Vt     = (u16*)(ws + 114819072);  // [96][64][1024] bf16 12.6MB (dead after attn)

    dim3 tb(32, 8);
    transpose4_768<<<dim3(24, 24, 4), tb, 0, stream>>>(Wq, Wk, Wv, Wo, Wqkvt, Wot);
    transpose_bf16<<<dim3(96, 24), tb, 0, stream>>>(W1, W1t, 768, 3072);
    transpose_bf16<<<dim3(24, 96), tb, 0, stream>>>(W2, W2t, 3072, 768);

    // h = LN1(x)
    ln_kernel<<<8192, 256, 0, stream>>>(x, g1, be1, h_bf);
    // qkv = h @ [Wq|Wk|Wv]  (bf16 out, coalesced epilogue, WGM remap)
    gemm_k32<<<dim3(18, 64), 256, 0, stream>>>(h_bf, Wqkvt, nullptr, nullptr, nullptr, qkv_bf, 2304, 768, 0);
    // Vt = per-head transpose of V
    vt_kernel<<<dim3(32, 2, 96), tb, 0, stream>>>(qkv_bf, Vt);
    // o = causal-softmax(q k^T * 768^-.5) v  (bf16 out) — balanced q-tile pairs
    attn_mfma<<<dim3(8, 96), 256, 0, stream>>>(qkv_bf, Vt, o_bf);
    // x2 = x + o @ Wo + bo  (f32 out)
    gemm_k32<<<dim3(6, 64), 256, 0, stream>>>(o_bf, Wot, bo, x, x2, nullptr, 768, 768, 0);
    // h = LN2(x2)
    ln_kernel<<<8192, 256, 0, stream>>>(x2, g2, be2, h_bf);
    // ff1 = gelu(h @ W1 + b1)  (bf16 out, coalesced epilogue, WGM remap)
    gemm_k32<<<dim3(24, 64), 256, 0, stream>>>(h_bf, W1t, b1, nullptr, nullptr, ff1_bf, 3072, 768, 1);
    // FF2 split-K=2: p_z = ff1 @ W2 (K-half z), then out = x2 + b2 + p0 + p1
    gemm_splitk<<<dim3(6, 64, 2), 256, 0, stream>>>(ff1_bf, W2t, p0_bf, p1_bf, 768, 3072);
    ff2_reduce<<<6144, 256, 0, stream>>>(x2, b2, p0_bf, p1_bf, out);
}

// Round 17
// 302.780 us; speedup vs baseline: 1.0190x; 1.0190x over previous
//
#include <hip/hip_runtime.h>
#include <math.h>
#include <stdint.h>

typedef unsigned short u16;
typedef unsigned int u32;
typedef __attribute__((ext_vector_type(8))) __bf16 bf16x8;
typedef __attribute__((ext_vector_type(4))) float f32x4;

#define AS1 __attribute__((address_space(1)))
#define AS3 __attribute__((address_space(3)))

__device__ __forceinline__ void stage16(const void* g, void* l) {
    __builtin_amdgcn_global_load_lds((const AS1 void*)(uintptr_t)g,
                                     (AS3 void*)(uintptr_t)l, 16, 0, 0);
}

__device__ __forceinline__ u16 f2bf(float f) {
    u32 u = __float_as_uint(f);
    u += 0x7fffu + ((u >> 16) & 1u);
    return (u16)(u >> 16);
}

__device__ __forceinline__ float bf2f(u16 v) {
    u32 u = ((u32)v) << 16;
    return __uint_as_float(u);
}

// tanh-GELU via sigmoid identity: 0.5x(1+tanh(a(x+bx^3))) = x * sigma(2a(x+b x^3)).
// max |dev| from exact erf-GELU ~3e-4 << 0.109 threshold; ~7 VALU ops vs erff's ~30.
__device__ __forceinline__ float fast_gelu(float x) {
    const float k = 1.5957691216057308f;   // 2*sqrt(2/pi)
    const float bb = 0.044715f;
    return x / (1.0f + __expf(-k * (x + bb * x * x * x)));
}

// ---------------- LayerNorm (f32 in): 256 thr per row of 768, bf16 out ----------------
__global__ __launch_bounds__(256) void ln_kernel(const float* __restrict__ x,
                                                 const float* __restrict__ g,
                                                 const float* __restrict__ b,
                                                 u16* __restrict__ out) {
    __shared__ float s8[8];
    int row = blockIdx.x;
    int tid = threadIdx.x;
    const int w = tid >> 6;
    const float* xr = x + (size_t)row * 768;
    float x0 = xr[tid], x1 = xr[tid + 256], x2 = xr[tid + 512];

    float sum = x0 + x1 + x2;
#pragma unroll
    for (int off = 32; off; off >>= 1) sum += __shfl_xor(sum, off);
    if ((tid & 63) == 0) s8[w] = sum;
    __syncthreads();
    float mu = (s8[0] + s8[1] + s8[2] + s8[3]) * (1.0f / 768.0f);

    float d0 = x0 - mu, d1 = x1 - mu, d2 = x2 - mu;
    float sq = d0 * d0 + d1 * d1 + d2 * d2;
#pragma unroll
    for (int off = 32; off; off >>= 1) sq += __shfl_xor(sq, off);
    if ((tid & 63) == 0) s8[4 + w] = sq;
    __syncthreads();
    float var = (s8[4] + s8[5] + s8[6] + s8[7]) * (1.0f / 768.0f);
    float rs = rsqrtf(var + 1e-5f);

    u16* orow = out + (size_t)row * 768;
    orow[tid]       = f2bf(d0 * rs * g[tid]       + b[tid]);
    orow[tid + 256] = f2bf(d1 * rs * g[tid + 256] + b[tid + 256]);
    orow[tid + 512] = f2bf(d2 * rs * g[tid + 512] + b[tid + 512]);
}

// ---------------- LayerNorm (bf16 in): for LN2 over the bf16 residual x2 ----------------
__global__ __launch_bounds__(256) void ln_kernel_bf(const u16* __restrict__ x,
                                                    const float* __restrict__ g,
                                                    const float* __restrict__ b,
                                                    u16* __restrict__ out) {
    __shared__ float s8[8];
    int row = blockIdx.x;
    int tid = threadIdx.x;
    const int w = tid >> 6;
    const u16* xr = x + (size_t)row * 768;
    float x0 = bf2f(xr[tid]), x1 = bf2f(xr[tid + 256]), x2 = bf2f(xr[tid + 512]);

    float sum = x0 + x1 + x2;
#pragma unroll
    for (int off = 32; off; off >>= 1) sum += __shfl_xor(sum, off);
    if ((tid & 63) == 0) s8[w] = sum;
    __syncthreads();
    float mu = (s8[0] + s8[1] + s8[2] + s8[3]) * (1.0f / 768.0f);

    float d0 = x0 - mu, d1 = x1 - mu, d2 = x2 - mu;
    float sq = d0 * d0 + d1 * d1 + d2 * d2;
#pragma unroll
    for (int off = 32; off; off >>= 1) sq += __shfl_xor(sq, off);
    if ((tid & 63) == 0) s8[4 + w] = sq;
    __syncthreads();
    float var = (s8[4] + s8[5] + s8[6] + s8[7]) * (1.0f / 768.0f);
    float rs = rsqrtf(var + 1e-5f);

    u16* orow = out + (size_t)row * 768;
    orow[tid]       = f2bf(d0 * rs * g[tid]       + b[tid]);
    orow[tid + 256] = f2bf(d1 * rs * g[tid + 256] + b[tid + 256]);
    orow[tid + 512] = f2bf(d2 * rs * g[tid + 512] + b[tid + 512]);
}

// ---------------- transpose + fp32->bf16 convert: W[K][N] -> Wt[N][K] ----------------
__global__ __launch_bounds__(256) void transpose_bf16(const float* __restrict__ W,
                                                      u16* __restrict__ Wt,
                                                      int K, int N) {
    __shared__ float t[32][33];
    int tx = threadIdx.x, ty = threadIdx.y;
    int n0 = blockIdx.x * 32, k0 = blockIdx.y * 32;
#pragma unroll
    for (int j = 0; j < 32; j += 8)
        t[ty + j][tx] = W[(size_t)(k0 + ty + j) * N + n0 + tx];
    __syncthreads();
#pragma unroll
    for (int j = 0; j < 32; j += 8)
        Wt[(size_t)(n0 + ty + j) * K + k0 + tx] = f2bf(t[tx][ty + j]);
}

// ---- fused 4x 768x768 transpose (Wq,Wk,Wv -> Wqkvt sections; Wo -> Wot) ----
__global__ __launch_bounds__(256) void transpose4_768(const float* __restrict__ Wq,
                                                      const float* __restrict__ Wk,
                                                      const float* __restrict__ Wv,
                                                      const float* __restrict__ Wo,
                                                      u16* __restrict__ Wqkvt,
                                                      u16* __restrict__ Wot) {
    __shared__ float t[32][33];
    const int z = blockIdx.z;
    const float* W = (z == 0) ? Wq : (z == 1) ? Wk : (z == 2) ? Wv : Wo;
    u16* Wt = (z == 3) ? Wot : (Wqkvt + (size_t)z * 768 * 768);
    int tx = threadIdx.x, ty = threadIdx.y;
    int n0 = blockIdx.x * 32, k0 = blockIdx.y * 32;
#pragma unroll
    for (int j = 0; j < 32; j += 8)
        t[ty + j][tx] = W[(size_t)(k0 + ty + j) * 768 + n0 + tx];
    __syncthreads();
#pragma unroll
    for (int j = 0; j < 32; j += 8)
        Wt[(size_t)(n0 + ty + j) * 768 + k0 + tx] = f2bf(t[tx][ty + j]);
}

// ---------------- V transpose: qkv v-region [8192][2304] -> Vt[96][64][1024] ----------------
__global__ __launch_bounds__(256) void vt_kernel(const u16* __restrict__ qkv,
                                                 u16* __restrict__ Vt) {
    __shared__ u16 t[32][34];
    const int tx = threadIdx.x, ty = threadIdx.y;
    const int s0 = blockIdx.x * 32, d0 = blockIdx.y * 32, bh = blockIdx.z;
    const int b = bh / 12, h = bh % 12;
#pragma unroll
    for (int j = 0; j < 32; j += 8)
        t[ty + j][tx] = qkv[((size_t)(b * 1024) + s0 + ty + j) * 2304 + 1536 + h * 64 + d0 + tx];
    __syncthreads();
#pragma unroll
    for (int j = 0; j < 32; j += 8)
        Vt[((size_t)bh * 64 + d0 + ty + j) * 1024 + s0 + tx] = t[tx][ty + j];
}

// ---------------- bf16 MFMA GEMM: 128^2, BK=32, triple buffer, 2-deep, unroll-3 ----------------
// WGM=8 supertile remap (FETCH 80->29MB measured). bf16 epilogue is LDS-coalesced
// and supports res-add (f32) for the Wo residual path.
__global__ __launch_bounds__(256, 3) void gemm_k32(
    const u16* __restrict__ A, const u16* __restrict__ Bt,
    const float* __restrict__ bias, const float* __restrict__ res,
    float* __restrict__ outF, u16* __restrict__ outB,
    int N, int K, int act) {
    __shared__ char lds[49152];
    const int tid = threadIdx.x, lane = tid & 63, wid = tid >> 6;
    const int l15 = lane & 15, lk = lane >> 4;
    const int wrow = (wid >> 1) * 64, wcol = (wid & 1) * 64;

    int wg = blockIdx.y * gridDim.x + blockIdx.x;
    const int nwg = gridDim.x * gridDim.y;
    wg = (wg & 7) * (nwg >> 3) + (wg >> 3);   // bijective XCD swizzle (nwg % 8 == 0)
    const int gx = gridDim.x;                  // WGM=8 supertile (gridDim.y % 8 == 0)
    const int strip = wg / (gx * 8);
    const int rem = wg - strip * gx * 8;
    const int brow = (strip * 8 + (rem & 7)) * 128;
    const int bcol = (rem >> 3) * 128;

    const size_t K2 = (size_t)K * 2;
    const char* Abase = (const char*)A + (size_t)brow * K2;
    const char* Bbase = (const char*)Bt + (size_t)bcol * K2;

    int srow[2], scol[2];
#pragma unroll
    for (int j = 0; j < 2; ++j) {
        const int L = j * 4096 + tid * 16;
        srow[j] = L >> 6;
        scol[j] = (L & 63) ^ (((srow[j] >> 1) & 3) << 4);
    }

    const int nt = K >> 5;  // 24 or 96: divisible by 3

    auto stage_tile = [&](int t, char* dst) {
#pragma unroll
        for (int j = 0; j < 2; ++j) {
            const size_t off = (size_t)srow[j] * K2 + (size_t)t * 64 + scol[j];
            stage16(Abase + off, dst + j * 4096 + tid * 16);
            stage16(Bbase + off, dst + 8192 + j * 4096 + tid * 16);
        }
    };

    f32x4 acc[4][4] = {};

    stage_tile(0, lds);
    stage_tile(1, lds + 16384);

    auto iter = [&](int t, char* buf, char* nxt) {
        if (t + 1 < nt) asm volatile("s_waitcnt vmcnt(4)\n\ts_barrier" ::: "memory");
        else            asm volatile("s_waitcnt vmcnt(0)\n\ts_barrier" ::: "memory");
        __builtin_amdgcn_sched_barrier(0);

        if (t + 2 < nt) stage_tile(t + 2, nxt);

        const char* As = buf;
        const char* Bs = buf + 8192;
        bf16x8 af[4], bfv[4];
#pragma unroll
        for (int m = 0; m < 4; ++m) {
            const int row = wrow + m * 16 + l15;
            af[m] = *(const bf16x8*)(As + row * 64 +
                                     ((lk * 16) ^ (((row >> 1) & 3) << 4)));
        }
#pragma unroll
        for (int n = 0; n < 4; ++n) {
            const int row = wcol + n * 16 + l15;
            bfv[n] = *(const bf16x8*)(Bs + row * 64 +
                                      ((lk * 16) ^ (((row >> 1) & 3) << 4)));
        }
        __builtin_amdgcn_s_setprio(1);
#pragma unroll
        for (int m = 0; m < 4; ++m)
#pragma unroll
            for (int n = 0; n < 4; ++n)
                acc[m][n] = __builtin_amdgcn_mfma_f32_16x16x32_bf16(af[m], bfv[n], acc[m][n], 0, 0, 0);
        __builtin_amdgcn_s_setprio(0);
    };

    for (int t = 0; t < nt; t += 3) {
        iter(t,     lds,         lds + 32768);
        iter(t + 1, lds + 16384, lds);
        iter(t + 2, lds + 32768, lds + 16384);
    }

    if (outB) {
        // coalesced bf16 epilogue via LDS (bufs 0-1 dead after final top barrier)
        u16* ctile = (u16*)lds;  // [128][128] u16 = 32KB
#pragma unroll
        for (int m = 0; m < 4; ++m)
#pragma unroll
            for (int n = 0; n < 4; ++n)
#pragma unroll
                for (int r = 0; r < 4; ++r) {
                    float v = acc[m][n][r];
                    int lrow = wrow + m * 16 + lk * 4 + r;
                    int col = wcol + n * 16 + l15;
                    if (bias) v += bias[bcol + col];
                    if (act) v = fast_gelu(v);
                    if (res) v += res[(size_t)(brow + lrow) * N + bcol + col];
                    ctile[lrow * 128 + col] = f2bf(v);
                }
        __syncthreads();
#pragma unroll
        for (int pass = 0; pass < 8; ++pass) {
            const int idx = pass * 256 + tid;
            const int row = idx >> 4;
            const int seg = idx & 15;
            *(bf16x8*)(outB + (size_t)(brow + row) * N + bcol + seg * 8) =
                *(const bf16x8*)(ctile + row * 128 + seg * 8);
        }
    } else {
#pragma unroll
        for (int m = 0; m < 4; ++m)
#pragma unroll
            for (int n = 0; n < 4; ++n)
#pragma unroll
                for (int r = 0; r < 4; ++r) {
                    int row = brow + wrow + m * 16 + lk * 4 + r;
                    int col = bcol + wcol + n * 16 + l15;
                    float v = acc[m][n][r];
                    if (bias) v += bias[col];
                    if (act) v = fast_gelu(v);
                    if (res) v += res[(size_t)row * N + col];
                    outF[(size_t)row * N + col] = v;
                }
    }
}

// ---------------- split-K=2 GEMM for FF2: z-half of K, bf16 partial out ----------------
__global__ __launch_bounds__(256, 3) void gemm_splitk(
    const u16* __restrict__ A, const u16* __restrict__ Bt,
    u16* __restrict__ p0, u16* __restrict__ p1, int N, int K) {
    __shared__ char lds[49152];
    const int tid = threadIdx.x, lane = tid & 63, wid = tid >> 6;
    const int l15 = lane & 15, lk = lane >> 4;
    const int wrow = (wid >> 1) * 64, wcol = (wid & 1) * 64;
    const int z = blockIdx.z;
    const int Kh = K >> 1;

    int wg = blockIdx.y * gridDim.x + blockIdx.x;
    const int nwg = gridDim.x * gridDim.y;
    wg = (wg & 7) * (nwg >> 3) + (wg >> 3);
    const int brow = (wg / gridDim.x) * 128;
    const int bcol = (wg % gridDim.x) * 128;

    const size_t K2 = (size_t)K * 2;
    const char* Abase = (const char*)A + (size_t)brow * K2 + (size_t)z * Kh * 2;
    const char* Bbase = (const char*)Bt + (size_t)bcol * K2 + (size_t)z * Kh * 2;

    int srow[2], scol[2];
#pragma unroll
    for (int j = 0; j < 2; ++j) {
        const int L = j * 4096 + tid * 16;
        srow[j] = L >> 6;
        scol[j] = (L & 63) ^ (((srow[j] >> 1) & 3) << 4);
    }

    const int nt = Kh >> 5;  // 48: divisible by 3

    auto stage_tile = [&](int t, char* dst) {
#pragma unroll
        for (int j = 0; j < 2; ++j) {
            const size_t off = (size_t)srow[j] * K2 + (size_t)t * 64 + scol[j];
            stage16(Abase + off, dst + j * 4096 + tid * 16);
            stage16(Bbase + off, dst + 8192 + j * 4096 + tid * 16);
        }
    };

    f32x4 acc[4][4] = {};

    stage_tile(0, lds);
    stage_tile(1, lds + 16384);

    auto iter = [&](int t, char* buf, char* nxt) {
        if (t + 1 < nt) asm volatile("s_waitcnt vmcnt(4)\n\ts_barrier" ::: "memory");
        else            asm volatile("s_waitcnt vmcnt(0)\n\ts_barrier" ::: "memory");
        __builtin_amdgcn_sched_barrier(0);

        if (t + 2 < nt) stage_tile(t + 2, nxt);

        const char* As = buf;
        const char* Bs = buf + 8192;
        bf16x8 af[4], bfv[4];
#pragma unroll
        for (int m = 0; m < 4; ++m) {
            const int row = wrow + m * 16 + l15;
            af[m] = *(const bf16x8*)(As + row * 64 +
                                     ((lk * 16) ^ (((row >> 1) & 3) << 4)));
        }
#pragma unroll
        for (int n = 0; n < 4; ++n) {
            const int row = wcol + n * 16 + l15;
            bfv[n] = *(const bf16x8*)(Bs + row * 64 +
                                      ((lk * 16) ^ (((row >> 1) & 3) << 4)));
        }
        __builtin_amdgcn_s_setprio(1);
#pragma unroll
        for (int m = 0; m < 4; ++m)
#pragma unroll
            for (int n = 0; n < 4; ++n)
                acc[m][n] = __builtin_amdgcn_mfma_f32_16x16x32_bf16(af[m], bfv[n], acc[m][n], 0, 0, 0);
        __builtin_amdgcn_s_setprio(0);
    };

    for (int t = 0; t < nt; t += 3) {
        iter(t,     lds,         lds + 32768);
        iter(t + 1, lds + 16384, lds);
        iter(t + 2, lds + 32768, lds + 16384);
    }

    u16* outP = z ? p1 : p0;
    u16* ctile = (u16*)lds;
#pragma unroll
    for (int m = 0; m < 4; ++m)
#pragma unroll
        for (int n = 0; n < 4; ++n)
#pragma unroll
            for (int r = 0; r < 4; ++r)
                ctile[(wrow + m * 16 + lk * 4 + r) * 128 + wcol + n * 16 + l15] =
                    f2bf(acc[m][n][r]);
    __syncthreads();
#pragma unroll
    for (int pass = 0; pass < 8; ++pass) {
        const int idx = pass * 256 + tid;
        const int row = idx >> 4;
        const int seg = idx & 15;
        *(bf16x8*)(outP + (size_t)(brow + row) * N + bcol + seg * 8) =
            *(const bf16x8*)(ctile + row * 128 + seg * 8);
    }
}

// ---------------- FF2 reduce: out = x2(bf16) + b2 + p0 + p1 ----------------
__global__ __launch_bounds__(256) void ff2_reduce(const u16* __restrict__ x2,
                                                  const float* __restrict__ b2,
                                                  const u16* __restrict__ p0,
                                                  const u16* __restrict__ p1,
                                                  float* __restrict__ out) {
    const size_t i = ((size_t)blockIdx.x * 256 + threadIdx.x) * 4;
    const ushort4 a = *(const ushort4*)(x2 + i);
    const int col = (int)(i % 768);
    const float4 bb = *(const float4*)(b2 + col);
    const ushort4 q0 = *(const ushort4*)(p0 + i);
    const ushort4 q1 = *(const ushort4*)(p1 + i);
    float4 o;
    o.x = bf2f(a.x) + bb.x + bf2f(q0.x) + bf2f(q1.x);
    o.y = bf2f(a.y) + bb.y + bf2f(q0.y) + bf2f(q1.y);
    o.z = bf2f(a.z) + bb.z + bf2f(q0.z) + bf2f(q1.z);
    o.w = bf2f(a.w) + bb.w + bf2f(q0.w) + bf2f(q1.w);
    *(float4*)(out + i) = o;
}

// ---------------- MFMA flash attention: balanced q-tile PAIRS, dbuf staging ----------------
__global__ __launch_bounds__(256) void attn_mfma(const u16* __restrict__ qkv,
                                                 const u16* __restrict__ Vt,
                                                 u16* __restrict__ obf) {
    __shared__ char lds[40960];
    const int tid = threadIdx.x, lane = tid & 63, w = tid >> 6;
    const int g = lane >> 4, l15 = lane & 15;

    int wg = blockIdx.y * gridDim.x + blockIdx.x;
    const int nwg = gridDim.x * gridDim.y;
    wg = (wg & 7) * (nwg >> 3) + (wg >> 3);
    const int p = wg / 96;               // 0..7: pair index (uniform per XCD chunk)
    const int bh = wg % 96;
    const int h = bh % 12, b = bh / 12;
    const float scale = 0.03608439182435161f;  // 768^-0.5 (C, not hs, per reference)

    const int sub = ((lane & 7) * 16) ^ ((lane >> 3) << 4);
    const int r0 = 16 * w + (lane >> 3);
    const int dstOff = 2 * w * 1024 + lane * 16;
    const int swzA = (l15 & 7) << 4;
    char* Pw = lds + 32768 + w * 2048;

#pragma unroll 1
    for (int half = 0; half < 2; ++half) {
        const int qb = half ? p : (15 - p);   // heavy tile first
        const int t0 = qb * 64;

        const size_t qrow = ((size_t)b * 1024 + t0 + 16 * w + l15) * 2304 + h * 64;
        const bf16x8 qf0 = *(const bf16x8*)(qkv + qrow + 8 * g);
        const bf16x8 qf1 = *(const bf16x8*)(qkv + qrow + 8 * g + 32);

        const char* kSrc = (const char*)qkv + ((size_t)(b * 1024 + r0) * 2304 + 768 + h * 64) * 2 + sub;
        const char* vSrc = (const char*)Vt + ((size_t)(bh * 64 + r0) * 1024) * 2 + sub;

        stage16(kSrc,            lds + dstOff);
        stage16(kSrc + 8 * 4608, lds + dstOff + 1024);
        stage16(vSrc,            lds + 8192 + dstOff);
        stage16(vSrc + 8 * 2048, lds + 8192 + dstOff + 1024);
        kSrc += 64 * 4608; vSrc += 128;
        __syncthreads();

        float m_r[4] = {-1e30f, -1e30f, -1e30f, -1e30f};
        float l_r[4] = {0.f, 0.f, 0.f, 0.f};
        f32x4 oacc[4] = {};

        for (int c = 0; c <= qb; ++c) {
            if (c < qb) {
                char* dst = lds + ((c + 1) & 1) * 16384;
                stage16(kSrc,            dst + dstOff);
                stage16(kSrc + 8 * 4608, dst + dstOff + 1024);
                stage16(vSrc,            dst + 8192 + dstOff);
                stage16(vSrc + 8 * 2048, dst + 8192 + dstOff + 1024);
                kSrc += 64 * 4608; vSrc += 128;
                asm volatile("s_waitcnt vmcnt(4)\n\ts_barrier" ::: "memory");
            } else {
                asm volatile("s_waitcnt vmcnt(0)\n\ts_barrier" ::: "memory");
            }
            __builtin_amdgcn_sched_barrier(0);

            const char* bufK = lds + (c & 1) * 16384;
            const char* bufV = bufK + 8192;

            f32x4 sacc[4] = {};
#pragma unroll
            for (int st = 0; st < 4; ++st) {
                const char* krow = bufK + (l15 + 16 * st) * 128;
                const bf16x8 kf0 = *(const bf16x8*)(krow + ((16 * g) ^ swzA));
                const bf16x8 kf1 = *(const bf16x8*)(krow + ((16 * g + 64) ^ swzA));
                sacc[st] = __builtin_amdgcn_mfma_f32_16x16x32_bf16(qf0, kf0, sacc[st], 0, 0, 0);
                sacc[st] = __builtin_amdgcn_mfma_f32_16x16x32_bf16(qf1, kf1, sacc[st], 0, 0, 0);
            }

            const bool diag = (c == qb);
#pragma unroll
            for (int r = 0; r < 4; ++r) {
                float sv0 = sacc[0][r] * scale, sv1 = sacc[1][r] * scale;
                float sv2 = sacc[2][r] * scale, sv3 = sacc[3][r] * scale;
                if (diag) {
                    const int trel = 16 * w + 4 * g + r;
                    if (l15 +  0 > trel) sv0 = -1e30f;
                    if (l15 + 16 > trel) sv1 = -1e30f;
                    if (l15 + 32 > trel) sv2 = -1e30f;
                    if (l15 + 48 > trel) sv3 = -1e30f;
                }
                float mx = fmaxf(fmaxf(sv0, sv1), fmaxf(sv2, sv3));
#pragma unroll
                for (int off = 1; off < 16; off <<= 1) mx = fmaxf(mx, __shfl_xor(mx, off));
                if (mx > m_r[r]) {
                    const float corr = __expf(m_r[r] - mx);
                    m_r[r] = mx;
                    l_r[r] *= corr;
                    oacc[0][r] *= corr; oacc[1][r] *= corr;
                    oacc[2][r] *= corr; oacc[3][r] *= corr;
                }
                const float p0 = __expf(sv0 - m_r[r]), p1 = __expf(sv1 - m_r[r]);
                const float p2 = __expf(sv2 - m_r[r]), p3 = __expf(sv3 - m_r[r]);
                float ps = p0 + p1 + p2 + p3;
#pragma unroll
                for (int off = 1; off < 16; off <<= 1) ps += __shfl_xor(ps, off);
                l_r[r] += ps;
                const int q = 4 * g + r;
                char* pr = Pw + q * 128;
                const int sw = (q & 7) << 4;
                *(u16*)(pr + ((l15 * 2 +  0) ^ sw)) = f2bf(p0);
                *(u16*)(pr + ((l15 * 2 + 32) ^ sw)) = f2bf(p1);
                *(u16*)(pr + ((l15 * 2 + 64) ^ sw)) = f2bf(p2);
                *(u16*)(pr + ((l15 * 2 + 96) ^ sw)) = f2bf(p3);
            }

#pragma unroll
            for (int kc = 0; kc < 2; ++kc) {
                const bf16x8 pa = *(const bf16x8*)(Pw + l15 * 128 + ((16 * g + 64 * kc) ^ swzA));
#pragma unroll
                for (int dt = 0; dt < 4; ++dt) {
                    const int d = l15 + 16 * dt;
                    const bf16x8 vf = *(const bf16x8*)(bufV + d * 128 +
                                       ((16 * g + 64 * kc) ^ ((d & 7) << 4)));
                    oacc[dt] = __builtin_amdgcn_mfma_f32_16x16x32_bf16(pa, vf, oacc[dt], 0, 0, 0);
                }
            }
            asm volatile("s_barrier" ::: "memory");
        }

        const size_t orow0 = ((size_t)b * 1024 + t0 + 16 * w) * 768 + h * 64;
#pragma unroll
        for (int r = 0; r < 4; ++r) {
            const float inv = 1.0f / l_r[r];
            const size_t orow = orow0 + (size_t)(4 * g + r) * 768;
#pragma unroll
            for (int dt = 0; dt < 4; ++dt)
                obf[orow + 16 * dt + l15] = f2bf(oacc[dt][r] * inv);
        }
    }
}

extern "C" void kernel_launch(void* const* d_in, const int* in_sizes, int n_in,
                              void* d_out, int out_size, void* d_ws, size_t ws_size,
                              hipStream_t stream) {
    const float* x   = (const float*)d_in[0];
    const float* Wq  = (const float*)d_in[1];
    const float* Wk  = (const float*)d_in[2];
    const float* Wv  = (const float*)d_in[3];
    const float* Wo  = (const float*)d_in[4];
    const float* bo  = (const float*)d_in[5];
    const float* W1  = (const float*)d_in[6];
    const float* b1  = (const float*)d_in[7];
    const float* W2  = (const float*)d_in[8];
    const float* b2  = (const float*)d_in[9];
    const float* g1  = (const float*)d_in[10];
    const float* be1 = (const float*)d_in[11];
    const float* g2  = (const float*)d_in[12];
    const float* be2 = (const float*)d_in[13];
    float* out = (float*)d_out;

    char* ws = (char*)d_ws;
    u16* qkv_bf = (u16*)(ws);              // [8192][2304] bf16  37.7MB (dead after attn)
    u16* ff1_bf = (u16*)(ws);              // [8192][3072] bf16  50.3MB (reuses qkv region)
    u16* x2b    = (u16*)(ws + 50331648);   // [8192][768]  bf16  12.6MB (residual stream)
    u16* h_bf   = (u16*)(ws + 75497472);   // [8192][768]  bf16  12.6MB (dead after FF1)
    u16* o_bf   = (u16*)(ws + 88080384);   // [8192][768]  bf16  12.6MB (dead after Wo)
    u16* p0_bf  = h_bf;                    // FF2 split-K partial 0 (reuses h_bf)
    u16* p1_bf  = o_bf;                    // FF2 split-K partial 1 (reuses o_bf)
    u16* Wqkvt  = (u16*)(ws + 100663296);  // [2304][768]  bf16   3.5MB
    u16* W1t    = (u16*)(ws + 104202240);  // [3072][768]  bf16   4.7MB
    u16* W2t    = (u16*)(ws + 108920832);  // [768][3072]  bf16   4.7MB
    u16* Wot    = (u16*)(ws + 113639424);  // [768][768]   bf16   1.2MB
    u16* Vt     = (u16*)(ws + 114819072);  // [96][64][1024] bf16 12.6MB (dead after attn)

    dim3 tb(32, 8);
    transpose4_768<<<dim3(24, 24, 4), tb, 0, stream>>>(Wq, Wk, Wv, Wo, Wqkvt, Wot);
    transpose_bf16<<<dim3(96, 24), tb, 0, stream>>>(W1, W1t, 768, 3072);
    transpose_bf16<<<dim3(24, 96), tb, 0, stream>>>(W2, W2t, 3072, 768);

    // h = LN1(x)
    ln_kernel<<<8192, 256, 0, stream>>>(x, g1, be1, h_bf);
    // qkv = h @ [Wq|Wk|Wv]  (bf16 out, coalesced epilogue, WGM remap)
    gemm_k32<<<dim3(18, 64), 256, 0, stream>>>(h_bf, Wqkvt, nullptr, nullptr, nullptr, qkv_bf, 2304, 768, 0);
    // Vt = per-head transpose of V
    vt_kernel<<<dim3(32, 2, 96), tb, 0, stream>>>(qkv_bf, Vt);
    // o = causal-softmax(q k^T * 768^-.5) v  (bf16 out) — balanced q-tile pairs
    attn_mfma<<<dim3(8, 96), 256, 0, stream>>>(qkv_bf, Vt, o_bf);
    // x2 = x + o @ Wo + bo  (bf16 residual out)
    gemm_k32<<<dim3(6, 64), 256, 0, stream>>>(o_bf, Wot, bo, x, nullptr, x2b, 768, 768, 0);
    // h = LN2(x2)
    ln_kernel_bf<<<8192, 256, 0, stream>>>(x2b, g2, be2, h_bf);
    // ff1 = gelu(h @ W1 + b1)  (bf16 out, fast-gelu, coalesced epilogue, WGM remap)
    gemm_k32<<<dim3(24, 64), 256, 0, stream>>>(h_bf, W1t, b1, nullptr, nullptr, ff1_bf, 3072, 768, 1);
    // FF2 split-K=2: p_z = ff1 @ W2 (K-half z), then out = x2 + b2 + p0 + p1
    gemm_splitk<<<dim3(6, 64, 2), 256, 0, stream>>>(ff1_bf, W2t, p0_bf, p1_bf, 768, 3072);
    ff2_reduce<<<6144, 256, 0, stream>>>(x2b, b2, p0_bf, p1_bf, out);
}